// Round 3
// baseline (411.786 us; speedup 1.0000x reference)
//
#include <hip/hip_runtime.h>

// ---------------------------------------------------------------------------
// MHA forward. B=2 S=4096 D=1024 H=16 DK=64. fp32 acc.
// R9 = R8 with compile fix (constexpr->const in unrolled loop) + final vmcnt
// drain. attn moves to 32x32x16 MFMA so the QK^T C-layout -> PV B-frag
// transform is a pure lane<->lane+32 exchange (v_cvt_pk_bf16_f32 +
// v_permlane32_swap): P never touches LDS. Removes 8KB/wave/kt LDS traffic,
// the Ps bank-conflict hotspot, and the write->read latency hop. Freed LDS
// buys a 3-buffer K/V pipeline with counted s_waitcnt vmcnt(2) (never drain
// to 0 in-loop) + raw s_barrier.
// R7 evidence: LDS pipe ~60us of 162 (24KB/wave/kt + 12.6M conflict cycles),
// true MFMA busy only ~12%, per-kt serial chain dominated by Ps round trip.
// ---------------------------------------------------------------------------

typedef __bf16 bf16x8 __attribute__((ext_vector_type(8)));
typedef __bf16 bf16x4 __attribute__((ext_vector_type(4)));
typedef float  f32x4  __attribute__((ext_vector_type(4)));
typedef float  f32x16 __attribute__((ext_vector_type(16)));
typedef unsigned int u32x4 __attribute__((ext_vector_type(4)));

#define MFMA16(a, b, c) __builtin_amdgcn_mfma_f32_16x16x32_bf16(a, b, c, 0, 0, 0)
#define MFMA32(a, b, c) __builtin_amdgcn_mfma_f32_32x32x16_bf16(a, b, c, 0, 0, 0)

constexpr int D_MODEL = 1024;
constexpr int SEQ     = 4096;
constexpr int BATCH   = 2;
constexpr int DKH     = 64;
constexpr int MROWS   = BATCH * SEQ;  // 8192
constexpr int QT      = 256;          // q rows per attn block
// softmax in exp2 domain: fold 1/sqrt(64) * log2(e) into Q projection
constexpr float QSCALE = 0.125f * 1.4426950408889634f;

__device__ __forceinline__ float fexp2(float x) {
#if __has_builtin(__builtin_amdgcn_exp2f)
  return __builtin_amdgcn_exp2f(x);  // raw v_exp_f32
#else
  return exp2f(x);
#endif
}

__device__ __forceinline__ void gll16(const void* g, void* l) {
  __builtin_amdgcn_global_load_lds(
      (const __attribute__((address_space(1))) void*)g,
      (__attribute__((address_space(3))) void*)l, 16, 0, 0);
}

__device__ __forceinline__ unsigned cvtpk(float lo, float hi) {
  unsigned r;
  asm("v_cvt_pk_bf16_f32 %0, %1, %2" : "=v"(r) : "v"(lo), "v"(hi));
  return r;
}

// ---------------------------------------------------------------- cast kernels
__global__ void cast_x3(const float* __restrict__ a, const float* __restrict__ b,
                        const float* __restrict__ c, __bf16* __restrict__ out) {
  const float* in = blockIdx.y == 0 ? a : (blockIdx.y == 1 ? b : c);
  __bf16* o = out + (size_t)blockIdx.y * MROWS * D_MODEL;
  int i = (blockIdx.x * 256 + threadIdx.x) * 4;
  float4 v = *(const float4*)(in + i);
  bf16x4 ov;
  ov[0] = (__bf16)v.x; ov[1] = (__bf16)v.y; ov[2] = (__bf16)v.z; ov[3] = (__bf16)v.w;
  *(bf16x4*)(o + i) = ov;
}

__global__ void cast_w4(const float* __restrict__ a, const float* __restrict__ b,
                        const float* __restrict__ c, const float* __restrict__ d,
                        __bf16* __restrict__ out) {
  const float* in = blockIdx.y == 0 ? a
                    : (blockIdx.y == 1 ? b : (blockIdx.y == 2 ? c : d));
  __bf16* o = out + (size_t)blockIdx.y * D_MODEL * D_MODEL;
  int i = (blockIdx.x * 256 + threadIdx.x) * 4;
  float4 v = *(const float4*)(in + i);
  bf16x4 ov;
  ov[0] = (__bf16)v.x; ov[1] = (__bf16)v.y; ov[2] = (__bf16)v.z; ov[3] = (__bf16)v.w;
  *(bf16x4*)(o + i) = ov;
}

// ------------------------------------------------------------------ GEMM (BT)
// C[M,N] = A[M,K] * W[N,K]^T + bias.  128x128 tile, BK=32, 4 waves (2x2),
// m97-style global_load_lds staging with swizzled per-lane source chunks.
// z==0 (Q proj, !OUTF32): output scaled by QSCALE.
// z==2 (V proj): output written TRANSPOSED per (b): Vt[(b*1024+n)][s].
template <bool OUTF32>
__global__ __launch_bounds__(256) void gemm_bt(
    const __bf16* __restrict__ Abase, const __bf16* __restrict__ Wbase,
    const float* __restrict__ b0, const float* __restrict__ b1,
    const float* __restrict__ b2, void* __restrict__ Obase) {
  constexpr int K = 1024, N = 1024;
  const int z = blockIdx.z;
  const __bf16* A = Abase + (size_t)z * MROWS * K;
  const __bf16* W = Wbase + (size_t)z * N * K;
  const float* bias = (z == 0) ? b0 : (z == 1 ? b1 : b2);

  const int bm0 = blockIdx.x * 128, bn0 = blockIdx.y * 128;
  const int tid = threadIdx.x;
  const int lane = tid & 63, w = tid >> 6;
  const int wr = w >> 1, wc = w & 1;
  const int quad = lane >> 4, l15 = lane & 15;

  __shared__ __align__(16) __bf16 As[128 * 32];
  __shared__ __align__(16) __bf16 Bs[128 * 32];

  const int drow = w * 16 + (lane >> 2);
  const int gch = (((lane & 3) ^ ((lane >> 2) & 3))) * 8;
  const __bf16* Ag0 = A + (size_t)(bm0 + drow) * K + gch;
  const __bf16* Ag1 = A + (size_t)(bm0 + drow + 64) * K + gch;
  const __bf16* Wg0 = W + (size_t)(bn0 + drow) * K + gch;
  const __bf16* Wg1 = W + (size_t)(bn0 + drow + 64) * K + gch;
  __bf16* lA0 = As + (w * 16) * 32;
  __bf16* lA1 = As + (64 + w * 16) * 32;
  __bf16* lB0 = Bs + (w * 16) * 32;
  __bf16* lB1 = Bs + (64 + w * 16) * 32;

  f32x4 acc[4][4];
  for (int i = 0; i < 4; i++)
    for (int j = 0; j < 4; j++) acc[i][j] = f32x4{0.f, 0.f, 0.f, 0.f};

  int aoff[4], boff[4];
  for (int i = 0; i < 4; i++) {
    aoff[i] = (wr * 64 + i * 16 + l15) * 32 + ((quad ^ (l15 & 3)) << 3);
    boff[i] = (wc * 64 + i * 16 + l15) * 32 + ((quad ^ (l15 & 3)) << 3);
  }

  for (int k0 = 0; k0 < K; k0 += 32) {
    __syncthreads();
    gll16(Ag0 + k0, lA0);
    gll16(Ag1 + k0, lA1);
    gll16(Wg0 + k0, lB0);
    gll16(Wg1 + k0, lB1);
    __syncthreads();
    bf16x8 af[4], bfr[4];
    for (int i = 0; i < 4; i++) af[i] = *(const bf16x8*)(As + aoff[i]);
    for (int j = 0; j < 4; j++) bfr[j] = *(const bf16x8*)(Bs + boff[j]);
    for (int i = 0; i < 4; i++)
      for (int j = 0; j < 4; j++) acc[i][j] = MFMA16(af[i], bfr[j], acc[i][j]);
  }

  if (!OUTF32 && z == 2) {
    __bf16* Vt = ((__bf16*)Obase) + (size_t)2 * MROWS * N;
    for (int j = 0; j < 4; j++) {
      int n = bn0 + wc * 64 + j * 16 + l15;
      float bv = bias[n];
      for (int i = 0; i < 4; i++) {
        int grow0 = bm0 + wr * 64 + i * 16 + quad * 4;
        int bb = grow0 >> 12, s = grow0 & 4095;
        bf16x4 ov;
        for (int r = 0; r < 4; r++) ov[r] = (__bf16)(acc[i][j][r] + bv);
        *(bf16x4*)(Vt + ((size_t)(bb * 1024 + n)) * SEQ + s) = ov;
      }
    }
  } else {
    const float scale = (!OUTF32 && z == 0) ? QSCALE : 1.0f;
    for (int j = 0; j < 4; j++) {
      int gcol = bn0 + wc * 64 + j * 16 + l15;
      float bv = bias[gcol];
      for (int i = 0; i < 4; i++) {
        int grow0 = bm0 + wr * 64 + i * 16 + quad * 4;
        for (int r = 0; r < 4; r++) {
          float v = (acc[i][j][r] + bv) * scale;
          size_t idx = (size_t)(grow0 + r) * N + gcol;
          if constexpr (OUTF32)
            ((float*)Obase)[idx] = v;
          else
            (((__bf16*)Obase) + (size_t)z * MROWS * N)[idx] = (__bf16)v;
        }
      }
    }
  }
}

// ----------------------------------------------------------- flash attention
// grid (16, 16, 2), block 512 (8 waves). Wave w owns q cols [w*32, w*32+32).
// 32x32x16 MFMA. St = K*Q^T (C: col=q=l&31, row=kv=(r&3)+8(r>>2)+4*hi).
// P stays in registers: cvt_pk_bf16 pairs + v_permlane32_swap_b32 build the
// PV B-frags (k = hi*8+j) directly.  O^T = V^T*P.  l = VALU row-sum + one
// epilogue shfl_xor(32).  K/V 64x64 tiles, 3-buffer pipeline, counted
// vmcnt(2) before a raw s_barrier (loads stay in flight across barriers).
__global__ __launch_bounds__(512, 4) void attn_kernel(
    const __bf16* __restrict__ Q, const __bf16* __restrict__ K,
    const __bf16* __restrict__ Vt, __bf16* __restrict__ O) {
  const int qt = blockIdx.x, h = blockIdx.y, b = blockIdx.z;
  const __bf16* Qg = Q + ((size_t)b * SEQ + qt * QT) * D_MODEL + h * DKH;
  const __bf16* Kg = K + (size_t)b * SEQ * D_MODEL + h * DKH;
  const __bf16* Vg = Vt + ((size_t)b * D_MODEL + h * DKH) * SEQ;

  // 3 buffers x (K 4096 + V 4096) bf16 = 48 KiB
  __shared__ __align__(16) __bf16 kvs[3 * 8192];

  const int tid = threadIdx.x;
  const int lane = tid & 63, w = tid >> 6;  // w in 0..7
  const int l31 = lane & 31, hi = lane >> 5;

  // staging: wave w loads rows w*8 .. w*8+7 of the 64-row K and V tiles.
  // stored[row][pos16B] = global chunk (pos ^ (row&7))   (XOR swizzle)
  const int dr = lane >> 3;                 // row & 7
  const int dch = ((lane & 7) ^ dr) * 8;    // swizzled source chunk (elements)
  const __bf16* KgT = Kg + (size_t)(w * 8 + dr) * D_MODEL + dch;
  const __bf16* VgT = Vg + (size_t)(w * 8 + dr) * SEQ + dch;

  // Q frags: B[k = d = dk*16 + hi*8 + j][n = q = w*32 + l31]
  bf16x8 qf[4];
  {
    const __bf16* Qrow = Qg + (size_t)(w * 32 + l31) * D_MODEL;
#pragma unroll
    for (int dk = 0; dk < 4; dk++)
      qf[dk] = *(const bf16x8*)(Qrow + dk * 16 + hi * 8);
  }

  // kt-invariant ds_read byte offsets: row-part + swizzled chunk.
  // rd4[x] serves K (x=dk) and V (x=c): (l31)*128 + ((2x+hi)^(lane&7))*16
  int rd4[4];
#pragma unroll
  for (int x = 0; x < 4; x++)
    rd4[x] = l31 * 128 + (((2 * x + hi) ^ (lane & 7)) << 4);

  f32x16 o2[2];  // o2[t] reg r: O^T[d=32t+(r&3)+8(r>>2)+4hi][q=w*32+l31]
#pragma unroll
  for (int t = 0; t < 2; t++)
#pragma unroll
    for (int r = 0; r < 16; r++) o2[t][r] = 0.f;
  float ol = 0.f;  // running sum over own kv-half (partner via shfl at end)

  // prologue: stage tile 0 into buf 0
  gll16(KgT, kvs + w * 512);
  gll16(VgT, kvs + 4096 + w * 512);
  const __bf16* kp = KgT + (size_t)64 * D_MODEL;  // source of next tile
  const __bf16* vp = VgT + 64;

#define ATTN_BODY(CUR, NXT, KS, VS)                                           \
  {                                                                           \
    gll16((KS), kvs + (NXT)*8192 + w * 512);                                  \
    gll16((VS), kvs + (NXT)*8192 + 4096 + w * 512);                           \
    asm volatile("s_waitcnt vmcnt(2)" ::: "memory");                          \
    __builtin_amdgcn_s_barrier();                                             \
    __builtin_amdgcn_sched_barrier(0);                                        \
    f32x16 st2[2];                                                            \
    _Pragma("unroll") for (int i = 0; i < 2; i++) {                           \
      _Pragma("unroll") for (int r = 0; r < 16; r++) st2[i][r] = 0.f;         \
    }                                                                         \
    _Pragma("unroll") for (int dk = 0; dk < 4; dk++) {                        \
      bf16x8 kf = *(const bf16x8*)((const char*)kvs + (CUR)*16384 + rd4[dk]); \
      st2[0] = MFMA32(kf, qf[dk], st2[0]);                                    \
    }                                                                         \
    _Pragma("unroll") for (int dk = 0; dk < 4; dk++) {                        \
      bf16x8 kf =                                                             \
          *(const bf16x8*)((const char*)kvs + (CUR)*16384 + 4096 + rd4[dk]);  \
      st2[1] = MFMA32(kf, qf[dk], st2[1]);                                    \
    }                                                                         \
    _Pragma("unroll") for (int i = 0; i < 2; i++) {                           \
      _Pragma("unroll") for (int r = 0; r < 16; r++) st2[i][r] =              \
          fexp2(st2[i][r]);                                                   \
    }                                                                         \
    _Pragma("unroll") for (int i = 0; i < 2; i++) {                           \
      float t0 = (st2[i][0] + st2[i][1]) + (st2[i][2] + st2[i][3]);           \
      float t1 = (st2[i][4] + st2[i][5]) + (st2[i][6] + st2[i][7]);           \
      float t2 = (st2[i][8] + st2[i][9]) + (st2[i][10] + st2[i][11]);         \
      float t3 = (st2[i][12] + st2[i][13]) + (st2[i][14] + st2[i][15]);       \
      ol += (t0 + t1) + (t2 + t3);                                            \
    }                                                                         \
    _Pragma("unroll") for (int c = 0; c < 4; c++) {                           \
      const int i0 = (2 * c) >> 2, rb0 = ((2 * c) & 3) * 4;                   \
      const int i1 = (2 * c + 1) >> 2, rb1 = ((2 * c + 1) & 3) * 4;           \
      unsigned v00 = cvtpk(st2[i0][rb0 + 0], st2[i0][rb0 + 1]);               \
      unsigned v01 = cvtpk(st2[i0][rb0 + 2], st2[i0][rb0 + 3]);               \
      unsigned v10 = cvtpk(st2[i1][rb1 + 0], st2[i1][rb1 + 1]);               \
      unsigned v11 = cvtpk(st2[i1][rb1 + 2], st2[i1][rb1 + 3]);               \
      asm("v_permlane32_swap_b32 %0, %1" : "+v"(v00), "+v"(v10));             \
      asm("v_permlane32_swap_b32 %0, %1" : "+v"(v01), "+v"(v11));             \
      u32x4 pw;                                                               \
      pw[0] = v00; pw[1] = v01; pw[2] = v10; pw[3] = v11;                     \
      bf16x8 pb = __builtin_bit_cast(bf16x8, pw);                             \
      bf16x8 va0 = *(const bf16x8*)((const char*)kvs + (CUR)*16384 + 8192 +   \
                                    rd4[c]);                                  \
      bf16x8 va1 = *(const bf16x8*)((const char*)kvs + (CUR)*16384 + 8192 +   \
                                    4096 + rd4[c]);                           \
      o2[0] = MFMA32(va0, pb, o2[0]);                                         \
      o2[1] = MFMA32(va1, pb, o2[1]);                                         \
    }                                                                         \
  }

  // kt = 0..62 in 21 x 3 (compile-time buffer indices), tail kt=63 separate.
  for (int kt3 = 0; kt3 < 21; kt3++) {
    ATTN_BODY(0, 1, kp, vp); kp += (size_t)64 * D_MODEL; vp += 64;
    ATTN_BODY(1, 2, kp, vp); kp += (size_t)64 * D_MODEL; vp += 64;
    ATTN_BODY(2, 0, kp, vp); kp += (size_t)64 * D_MODEL; vp += 64;
  }
  // kt = 63 (CUR = 63%3 = 0): dummy re-stage of tile 0 keeps vmcnt uniform.
  ATTN_BODY(0, 1, KgT, VgT);
#undef ATTN_BODY
  // drain the dummy DMA before the wave exits / epilogue stores
  asm volatile("s_waitcnt vmcnt(0)" ::: "memory");

  // epilogue: l = own + partner(lane^32); O^T[d][q] -> AO[q][h*64+d]
  float lother = __shfl_xor(ol, 32, 64);
  float inv = 1.f / (ol + lother);
  const int qrow = qt * QT + w * 32 + l31;
  __bf16* og = O + ((size_t)b * SEQ + qrow) * D_MODEL + h * DKH;
#pragma unroll
  for (int t = 0; t < 2; t++) {
#pragma unroll
    for (int g = 0; g < 4; g++) {
      bf16x4 ov;
#pragma unroll
      for (int e = 0; e < 4; e++) ov[e] = (__bf16)(o2[t][4 * g + e] * inv);
      *(bf16x4*)(og + 32 * t + 8 * g + 4 * hi) = ov;
    }
  }
}

// ---------------------------------------------------------------------------
extern "C" void kernel_launch(void* const* d_in, const int* in_sizes, int n_in,
                              void* d_out, int out_size, void* d_ws,
                              size_t ws_size, hipStream_t stream) {
  const float* q  = (const float*)d_in[0];
  const float* k  = (const float*)d_in[1];
  const float* v  = (const float*)d_in[2];
  const float* Wq = (const float*)d_in[3];
  const float* bq = (const float*)d_in[4];
  const float* Wk = (const float*)d_in[5];
  const float* bk = (const float*)d_in[6];
  const float* Wv = (const float*)d_in[7];
  const float* bv = (const float*)d_in[8];
  const float* Wo = (const float*)d_in[9];
  const float* bo = (const float*)d_in[10];

  const size_t MD = (size_t)MROWS * D_MODEL;
  const size_t WW = (size_t)D_MODEL * D_MODEL;

  __bf16* ws  = (__bf16*)d_ws;
  __bf16* Xq  = ws;                // Xq,Xk,Xv contiguous
  __bf16* Wqb = Xq + 3 * MD;       // Wq,Wk,Wv,Wo contiguous
  __bf16* Qp  = Wqb + 4 * WW;      // z=0 Q (scaled), z=1 K, z=2 V^T
  __bf16* Kp  = Qp + MD;
  __bf16* Vtp = Kp + MD;           // transposed: [(b*1024 + h*64 + d)][s]
  __bf16* AO  = Vtp + MD;

  cast_x3<<<dim3(8192, 3), 256, 0, stream>>>(q, k, v, Xq);
  cast_w4<<<dim3(1024, 4), 256, 0, stream>>>(Wq, Wk, Wv, Wo, Wqb);

  gemm_bt<false><<<dim3(MROWS / 128, D_MODEL / 128, 3), 256, 0, stream>>>(
      Xq, Wqb, bq, bk, bv, (void*)Qp);

  attn_kernel<<<dim3(SEQ / QT, 16, BATCH), 512, 0, stream>>>(Qp, Kp, Vtp, AO);

  gemm_bt<true><<<dim3(MROWS / 128, D_MODEL / 128, 1), 256, 0, stream>>>(
      AO, Wqb + 3 * WW, bo, bo, bo, d_out);
}

// Round 4
// 384.142 us; speedup vs baseline: 1.0720x; 1.0720x over previous
//
#include <hip/hip_runtime.h>

// ---------------------------------------------------------------------------
// MHA forward. B=2 S=4096 D=1024 H=16 DK=64. fp32 acc.
// R10: GEMM rewrite. R9 totals showed GEMMs ~200us of 411 (attn only 150):
// the old 128x128/BK=32 structure pays 2 barriers + full vmcnt drain per
// K-step (64 drains/block). New gemm_bt: BM=128 BN=256 BK=64, 8 waves
// (2Mx4N, 64x64 per wave), 512 thr, 3-slot LDS ring (144KB), 2-tile
// prefetch lookahead, ONE s_barrier per K-tile, counted s_waitcnt vmcnt(6)
// (never 0 in loop) -- the same pipeline proven in attn this session.
// XOR chunk swizzle on A/B rows for conflict-reduced ds_read_b128.
// Grid: proj 64x4x3 = 768 = 3 exact full-GPU rounds; out 256 = 1 round.
// attn unchanged from R9 (150us).
// ---------------------------------------------------------------------------

typedef __bf16 bf16x8 __attribute__((ext_vector_type(8)));
typedef __bf16 bf16x4 __attribute__((ext_vector_type(4)));
typedef float  f32x4  __attribute__((ext_vector_type(4)));
typedef float  f32x16 __attribute__((ext_vector_type(16)));
typedef unsigned int u32x4 __attribute__((ext_vector_type(4)));

#define MFMA16(a, b, c) __builtin_amdgcn_mfma_f32_16x16x32_bf16(a, b, c, 0, 0, 0)
#define MFMA32(a, b, c) __builtin_amdgcn_mfma_f32_32x32x16_bf16(a, b, c, 0, 0, 0)

constexpr int D_MODEL = 1024;
constexpr int SEQ     = 4096;
constexpr int BATCH   = 2;
constexpr int DKH     = 64;
constexpr int MROWS   = BATCH * SEQ;  // 8192
constexpr int QT      = 256;          // q rows per attn block
// softmax in exp2 domain: fold 1/sqrt(64) * log2(e) into Q projection
constexpr float QSCALE = 0.125f * 1.4426950408889634f;

__device__ __forceinline__ float fexp2(float x) {
#if __has_builtin(__builtin_amdgcn_exp2f)
  return __builtin_amdgcn_exp2f(x);  // raw v_exp_f32
#else
  return exp2f(x);
#endif
}

__device__ __forceinline__ void gll16(const void* g, void* l) {
  __builtin_amdgcn_global_load_lds(
      (const __attribute__((address_space(1))) void*)g,
      (__attribute__((address_space(3))) void*)l, 16, 0, 0);
}

__device__ __forceinline__ unsigned cvtpk(float lo, float hi) {
  unsigned r;
  asm("v_cvt_pk_bf16_f32 %0, %1, %2" : "=v"(r) : "v"(lo), "v"(hi));
  return r;
}

// ---------------------------------------------------------------- cast kernels
__global__ void cast_x3(const float* __restrict__ a, const float* __restrict__ b,
                        const float* __restrict__ c, __bf16* __restrict__ out) {
  const float* in = blockIdx.y == 0 ? a : (blockIdx.y == 1 ? b : c);
  __bf16* o = out + (size_t)blockIdx.y * MROWS * D_MODEL;
  int i = (blockIdx.x * 256 + threadIdx.x) * 4;
  float4 v = *(const float4*)(in + i);
  bf16x4 ov;
  ov[0] = (__bf16)v.x; ov[1] = (__bf16)v.y; ov[2] = (__bf16)v.z; ov[3] = (__bf16)v.w;
  *(bf16x4*)(o + i) = ov;
}

__global__ void cast_w4(const float* __restrict__ a, const float* __restrict__ b,
                        const float* __restrict__ c, const float* __restrict__ d,
                        __bf16* __restrict__ out) {
  const float* in = blockIdx.y == 0 ? a
                    : (blockIdx.y == 1 ? b : (blockIdx.y == 2 ? c : d));
  __bf16* o = out + (size_t)blockIdx.y * D_MODEL * D_MODEL;
  int i = (blockIdx.x * 256 + threadIdx.x) * 4;
  float4 v = *(const float4*)(in + i);
  bf16x4 ov;
  ov[0] = (__bf16)v.x; ov[1] = (__bf16)v.y; ov[2] = (__bf16)v.z; ov[3] = (__bf16)v.w;
  *(bf16x4*)(o + i) = ov;
}

// ------------------------------------------------------------------ GEMM (BT)
// C[M,N] = A[M,K] * W[N,K]^T + bias.  BM=128 BN=256 BK=64, 8 waves (2Mx4N,
// 64x64/wave), 3-slot LDS ring, 2-tile prefetch, vmcnt(6) counted, one
// barrier per K-tile.  K-tile T: compute slot T%3, stage T+2 into (T+2)%3.
// z==0 (Q proj, !OUTF32): output scaled by QSCALE.
// z==2 (V proj): output written TRANSPOSED per (b): Vt[(b*1024+n)][s].
template <bool OUTF32>
__global__ __launch_bounds__(512, 2) void gemm_bt(
    const __bf16* __restrict__ Abase, const __bf16* __restrict__ Wbase,
    const float* __restrict__ b0, const float* __restrict__ b1,
    const float* __restrict__ b2, void* __restrict__ Obase) {
  constexpr int K = 1024, N = 1024;
  const int z = blockIdx.z;
  const __bf16* A = Abase + (size_t)z * MROWS * K;
  const __bf16* W = Wbase + (size_t)z * N * K;
  const float* bias = (z == 0) ? b0 : (z == 1 ? b1 : b2);

  const int bm0 = blockIdx.x * 128, bn0 = blockIdx.y * 256;
  const int tid = threadIdx.x;
  const int lane = tid & 63, w = tid >> 6;  // 8 waves
  const int wm = w >> 2, wn = w & 3;        // 2M x 4N
  const int quad = lane >> 4, l15 = lane & 15;

  // 3 ring slots: A 128x64 (8192 elem), B 256x64 (16384 elem). 144KB total.
  __shared__ __align__(16) __bf16 lds[3 * 8192 + 3 * 16384];
  constexpr int AS0 = 0, AS1 = 8192, AS2 = 16384;
  constexpr int BS0 = 24576, BS1 = 40960, BS2 = 57344;

  // staging: per issue a wave covers 8 rows x 8 chunks of 16B.
  // stored chunk position p holds global chunk p ^ (row&7).
  const int dr8 = lane >> 3;               // row & 7
  const int dc8 = ((lane & 7) ^ dr8) * 8;  // swizzled source chunk (elems)
  const __bf16* Ag0 = A + (size_t)(bm0 + w * 8 + dr8) * K + dc8;
  const __bf16* Ag1 = A + (size_t)(bm0 + 64 + w * 8 + dr8) * K + dc8;
  const __bf16* Wg0 = W + (size_t)(bn0 + w * 8 + dr8) * K + dc8;
  const __bf16* Wg1 = W + (size_t)(bn0 + 64 + w * 8 + dr8) * K + dc8;
  const __bf16* Wg2 = W + (size_t)(bn0 + 128 + w * 8 + dr8) * K + dc8;
  const __bf16* Wg3 = W + (size_t)(bn0 + 192 + w * 8 + dr8) * K + dc8;
  const int ldw = w * 512;  // wave's 8-row stripe (elems)

  f32x4 acc[4][4];
#pragma unroll
  for (int i = 0; i < 4; i++)
#pragma unroll
    for (int j = 0; j < 4; j++) acc[i][j] = f32x4{0.f, 0.f, 0.f, 0.f};

  // ds_read byte offsets (kk=0); kk=1 = ^64 (chunk quad -> quad+4)
  int aoff[4], boff[4];
#pragma unroll
  for (int i = 0; i < 4; i++) {
    aoff[i] = (wm * 64 + i * 16 + l15) * 128 + ((quad ^ (l15 & 7)) << 4);
    boff[i] = (wn * 64 + i * 16 + l15) * 128 + ((quad ^ (l15 & 7)) << 4);
  }

#define GSTAGE(PA_, PB_, KO)                         \
  gll16(Ag0 + (KO), lds + (PA_) + ldw);              \
  gll16(Ag1 + (KO), lds + (PA_) + 4096 + ldw);       \
  gll16(Wg0 + (KO), lds + (PB_) + ldw);              \
  gll16(Wg1 + (KO), lds + (PB_) + 4096 + ldw);       \
  gll16(Wg2 + (KO), lds + (PB_) + 8192 + ldw);       \
  gll16(Wg3 + (KO), lds + (PB_) + 12288 + ldw);

#define GBODY(CA_, CB_, PA_, PB_, KO)                                         \
  {                                                                           \
    asm volatile("s_waitcnt vmcnt(6)" ::: "memory");                          \
    __builtin_amdgcn_s_barrier();                                             \
    __builtin_amdgcn_sched_barrier(0);                                        \
    GSTAGE(PA_, PB_, KO);                                                     \
    __builtin_amdgcn_s_setprio(1);                                            \
    bf16x8 a0[4], b0f[4], a1[4], b1f[4];                                      \
    _Pragma("unroll") for (int i = 0; i < 4; i++) a0[i] =                     \
        *(const bf16x8*)((const char*)lds + (CA_)*2 + aoff[i]);               \
    _Pragma("unroll") for (int j = 0; j < 4; j++) b0f[j] =                    \
        *(const bf16x8*)((const char*)lds + (CB_)*2 + boff[j]);               \
    _Pragma("unroll") for (int i = 0; i < 4; i++) a1[i] =                     \
        *(const bf16x8*)((const char*)lds + (CA_)*2 + (aoff[i] ^ 64));        \
    _Pragma("unroll") for (int j = 0; j < 4; j++) b1f[j] =                    \
        *(const bf16x8*)((const char*)lds + (CB_)*2 + (boff[j] ^ 64));        \
    _Pragma("unroll") for (int i = 0; i < 4; i++)                             \
      _Pragma("unroll") for (int j = 0; j < 4; j++) acc[i][j] =               \
          MFMA16(a0[i], b0f[j], acc[i][j]);                                   \
    _Pragma("unroll") for (int i = 0; i < 4; i++)                             \
      _Pragma("unroll") for (int j = 0; j < 4; j++) acc[i][j] =               \
          MFMA16(a1[i], b1f[j], acc[i][j]);                                   \
    __builtin_amdgcn_s_setprio(0);                                            \
  }

  // prologue: stage K-tiles 0 and 1
  GSTAGE(AS0, BS0, 0);
  GSTAGE(AS1, BS1, 64);
  // K-tiles 0..11 (stage 2..13)
  for (int t3 = 0; t3 < 4; t3++) {
    const int ko = t3 * 192;
    GBODY(AS0, BS0, AS2, BS2, ko + 128);
    GBODY(AS1, BS1, AS0, BS0, ko + 192);
    GBODY(AS2, BS2, AS1, BS1, ko + 256);
  }
  GBODY(AS0, BS0, AS2, BS2, 896);  // tile 12, stage 14
  GBODY(AS1, BS1, AS0, BS0, 960);  // tile 13, stage 15
  GBODY(AS2, BS2, AS1, BS1, 0);    // tile 14, dummy stage (dead slot)
  GBODY(AS0, BS0, AS2, BS2, 0);    // tile 15, dummy stage (dead slot)
  asm volatile("s_waitcnt vmcnt(0)" ::: "memory");
#undef GBODY
#undef GSTAGE

  if (!OUTF32 && z == 2) {
    __bf16* Vt = ((__bf16*)Obase) + (size_t)2 * MROWS * N;
    for (int j = 0; j < 4; j++) {
      int n = bn0 + wn * 64 + j * 16 + l15;
      float bv = bias[n];
      for (int i = 0; i < 4; i++) {
        int grow0 = bm0 + wm * 64 + i * 16 + quad * 4;
        int bb = grow0 >> 12, s = grow0 & 4095;
        bf16x4 ov;
        for (int r = 0; r < 4; r++) ov[r] = (__bf16)(acc[i][j][r] + bv);
        *(bf16x4*)(Vt + ((size_t)(bb * 1024 + n)) * SEQ + s) = ov;
      }
    }
  } else {
    const float scale = (!OUTF32 && z == 0) ? QSCALE : 1.0f;
    for (int j = 0; j < 4; j++) {
      int gcol = bn0 + wn * 64 + j * 16 + l15;
      float bv = bias[gcol];
      for (int i = 0; i < 4; i++) {
        int grow0 = bm0 + wm * 64 + i * 16 + quad * 4;
        for (int r = 0; r < 4; r++) {
          float v = (acc[i][j][r] + bv) * scale;
          size_t idx = (size_t)(grow0 + r) * N + gcol;
          if constexpr (OUTF32)
            ((float*)Obase)[idx] = v;
          else
            (((__bf16*)Obase) + (size_t)z * MROWS * N)[idx] = (__bf16)v;
        }
      }
    }
  }
}

// ----------------------------------------------------------- flash attention
// grid (16, 16, 2), block 512 (8 waves). Wave w owns q cols [w*32, w*32+32).
// 32x32x16 MFMA. St = K*Q^T (C: col=q=l&31, row=kv=(r&3)+8(r>>2)+4*hi).
// P stays in registers: cvt_pk_bf16 pairs + v_permlane32_swap_b32 build the
// PV B-frags (k = hi*8+j) directly.  O^T = V^T*P.  l = VALU row-sum + one
// epilogue shfl_xor(32).  K/V 64x64 tiles, 3-buffer pipeline, counted
// vmcnt(2) before a raw s_barrier (loads stay in flight across barriers).
__global__ __launch_bounds__(512, 4) void attn_kernel(
    const __bf16* __restrict__ Q, const __bf16* __restrict__ K,
    const __bf16* __restrict__ Vt, __bf16* __restrict__ O) {
  const int qt = blockIdx.x, h = blockIdx.y, b = blockIdx.z;
  const __bf16* Qg = Q + ((size_t)b * SEQ + qt * QT) * D_MODEL + h * DKH;
  const __bf16* Kg = K + (size_t)b * SEQ * D_MODEL + h * DKH;
  const __bf16* Vg = Vt + ((size_t)b * D_MODEL + h * DKH) * SEQ;

  // 3 buffers x (K 4096 + V 4096) bf16 = 48 KiB
  __shared__ __align__(16) __bf16 kvs[3 * 8192];

  const int tid = threadIdx.x;
  const int lane = tid & 63, w = tid >> 6;  // w in 0..7
  const int l31 = lane & 31, hi = lane >> 5;

  // staging: wave w loads rows w*8 .. w*8+7 of the 64-row K and V tiles.
  // stored[row][pos16B] = global chunk (pos ^ (row&7))   (XOR swizzle)
  const int dr = lane >> 3;                 // row & 7
  const int dch = ((lane & 7) ^ dr) * 8;    // swizzled source chunk (elements)
  const __bf16* KgT = Kg + (size_t)(w * 8 + dr) * D_MODEL + dch;
  const __bf16* VgT = Vg + (size_t)(w * 8 + dr) * SEQ + dch;

  // Q frags: B[k = d = dk*16 + hi*8 + j][n = q = w*32 + l31]
  bf16x8 qf[4];
  {
    const __bf16* Qrow = Qg + (size_t)(w * 32 + l31) * D_MODEL;
#pragma unroll
    for (int dk = 0; dk < 4; dk++)
      qf[dk] = *(const bf16x8*)(Qrow + dk * 16 + hi * 8);
  }

  // kt-invariant ds_read byte offsets: row-part + swizzled chunk.
  // rd4[x] serves K (x=dk) and V (x=c): (l31)*128 + ((2x+hi)^(lane&7))*16
  int rd4[4];
#pragma unroll
  for (int x = 0; x < 4; x++)
    rd4[x] = l31 * 128 + (((2 * x + hi) ^ (lane & 7)) << 4);

  f32x16 o2[2];  // o2[t] reg r: O^T[d=32t+(r&3)+8(r>>2)+4hi][q=w*32+l31]
#pragma unroll
  for (int t = 0; t < 2; t++)
#pragma unroll
    for (int r = 0; r < 16; r++) o2[t][r] = 0.f;
  float ol = 0.f;  // running sum over own kv-half (partner via shfl at end)

  // prologue: stage tile 0 into buf 0
  gll16(KgT, kvs + w * 512);
  gll16(VgT, kvs + 4096 + w * 512);
  const __bf16* kp = KgT + (size_t)64 * D_MODEL;  // source of next tile
  const __bf16* vp = VgT + 64;

#define ATTN_BODY(CUR, NXT, KS, VS)                                           \
  {                                                                           \
    gll16((KS), kvs + (NXT)*8192 + w * 512);                                  \
    gll16((VS), kvs + (NXT)*8192 + 4096 + w * 512);                           \
    asm volatile("s_waitcnt vmcnt(2)" ::: "memory");                          \
    __builtin_amdgcn_s_barrier();                                             \
    __builtin_amdgcn_sched_barrier(0);                                        \
    f32x16 st2[2];                                                            \
    _Pragma("unroll") for (int i = 0; i < 2; i++) {                           \
      _Pragma("unroll") for (int r = 0; r < 16; r++) st2[i][r] = 0.f;         \
    }                                                                         \
    _Pragma("unroll") for (int dk = 0; dk < 4; dk++) {                        \
      bf16x8 kf = *(const bf16x8*)((const char*)kvs + (CUR)*16384 + rd4[dk]); \
      st2[0] = MFMA32(kf, qf[dk], st2[0]);                                    \
    }                                                                         \
    _Pragma("unroll") for (int dk = 0; dk < 4; dk++) {                        \
      bf16x8 kf =                                                             \
          *(const bf16x8*)((const char*)kvs + (CUR)*16384 + 4096 + rd4[dk]);  \
      st2[1] = MFMA32(kf, qf[dk], st2[1]);                                    \
    }                                                                         \
    _Pragma("unroll") for (int i = 0; i < 2; i++) {                           \
      _Pragma("unroll") for (int r = 0; r < 16; r++) st2[i][r] =              \
          fexp2(st2[i][r]);                                                   \
    }                                                                         \
    _Pragma("unroll") for (int i = 0; i < 2; i++) {                           \
      float t0 = (st2[i][0] + st2[i][1]) + (st2[i][2] + st2[i][3]);           \
      float t1 = (st2[i][4] + st2[i][5]) + (st2[i][6] + st2[i][7]);           \
      float t2 = (st2[i][8] + st2[i][9]) + (st2[i][10] + st2[i][11]);         \
      float t3 = (st2[i][12] + st2[i][13]) + (st2[i][14] + st2[i][15]);       \
      ol += (t0 + t1) + (t2 + t3);                                            \
    }                                                                         \
    _Pragma("unroll") for (int c = 0; c < 4; c++) {                           \
      const int i0 = (2 * c) >> 2, rb0 = ((2 * c) & 3) * 4;                   \
      const int i1 = (2 * c + 1) >> 2, rb1 = ((2 * c + 1) & 3) * 4;           \
      unsigned v00 = cvtpk(st2[i0][rb0 + 0], st2[i0][rb0 + 1]);               \
      unsigned v01 = cvtpk(st2[i0][rb0 + 2], st2[i0][rb0 + 3]);               \
      unsigned v10 = cvtpk(st2[i1][rb1 + 0], st2[i1][rb1 + 1]);               \
      unsigned v11 = cvtpk(st2[i1][rb1 + 2], st2[i1][rb1 + 3]);               \
      asm("v_permlane32_swap_b32 %0, %1" : "+v"(v00), "+v"(v10));             \
      asm("v_permlane32_swap_b32 %0, %1" : "+v"(v01), "+v"(v11));             \
      u32x4 pw;                                                               \
      pw[0] = v00; pw[1] = v01; pw[2] = v10; pw[3] = v11;                     \
      bf16x8 pb = __builtin_bit_cast(bf16x8, pw);                             \
      bf16x8 va0 = *(const bf16x8*)((const char*)kvs + (CUR)*16384 + 8192 +   \
                                    rd4[c]);                                  \
      bf16x8 va1 = *(const bf16x8*)((const char*)kvs + (CUR)*16384 + 8192 +   \
                                    4096 + rd4[c]);                           \
      o2[0] = MFMA32(va0, pb, o2[0]);                                         \
      o2[1] = MFMA32(va1, pb, o2[1]);                                         \
    }                                                                         \
  }

  // kt = 0..62 in 21 x 3 (compile-time buffer indices), tail kt=63 separate.
  for (int kt3 = 0; kt3 < 21; kt3++) {
    ATTN_BODY(0, 1, kp, vp); kp += (size_t)64 * D_MODEL; vp += 64;
    ATTN_BODY(1, 2, kp, vp); kp += (size_t)64 * D_MODEL; vp += 64;
    ATTN_BODY(2, 0, kp, vp); kp += (size_t)64 * D_MODEL; vp += 64;
  }
  // kt = 63 (CUR = 63%3 = 0): dummy re-stage of tile 0 keeps vmcnt uniform.
  ATTN_BODY(0, 1, KgT, VgT);
#undef ATTN_BODY
  // drain the dummy DMA before the wave exits / epilogue stores
  asm volatile("s_waitcnt vmcnt(0)" ::: "memory");

  // epilogue: l = own + partner(lane^32); O^T[d][q] -> AO[q][h*64+d]
  float lother = __shfl_xor(ol, 32, 64);
  float inv = 1.f / (ol + lother);
  const int qrow = qt * QT + w * 32 + l31;
  __bf16* og = O + ((size_t)b * SEQ + qrow) * D_MODEL + h * DKH;
#pragma unroll
  for (int t = 0; t < 2; t++) {
#pragma unroll
    for (int g = 0; g < 4; g++) {
      bf16x4 ov;
#pragma unroll
      for (int e = 0; e < 4; e++) ov[e] = (__bf16)(o2[t][4 * g + e] * inv);
      *(bf16x4*)(og + 32 * t + 8 * g + 4 * hi) = ov;
    }
  }
}

// ---------------------------------------------------------------------------
extern "C" void kernel_launch(void* const* d_in, const int* in_sizes, int n_in,
                              void* d_out, int out_size, void* d_ws,
                              size_t ws_size, hipStream_t stream) {
  const float* q  = (const float*)d_in[0];
  const float* k  = (const float*)d_in[1];
  const float* v  = (const float*)d_in[2];
  const float* Wq = (const float*)d_in[3];
  const float* bq = (const float*)d_in[4];
  const float* Wk = (const float*)d_in[5];
  const float* bk = (const float*)d_in[6];
  const float* Wv = (const float*)d_in[7];
  const float* bv = (const float*)d_in[8];
  const float* Wo = (const float*)d_in[9];
  const float* bo = (const float*)d_in[10];

  const size_t MD = (size_t)MROWS * D_MODEL;
  const size_t WW = (size_t)D_MODEL * D_MODEL;

  __bf16* ws  = (__bf16*)d_ws;
  __bf16* Xq  = ws;                // Xq,Xk,Xv contiguous
  __bf16* Wqb = Xq + 3 * MD;       // Wq,Wk,Wv,Wo contiguous
  __bf16* Qp  = Wqb + 4 * WW;      // z=0 Q (scaled), z=1 K, z=2 V^T
  __bf16* Kp  = Qp + MD;
  __bf16* Vtp = Kp + MD;           // transposed: [(b*1024 + h*64 + d)][s]
  __bf16* AO  = Vtp + MD;

  cast_x3<<<dim3(8192, 3), 256, 0, stream>>>(q, k, v, Xq);
  cast_w4<<<dim3(1024, 4), 256, 0, stream>>>(Wq, Wk, Wv, Wo, Wqb);

  gemm_bt<false><<<dim3(MROWS / 128, D_MODEL / 256, 3), 512, 0, stream>>>(
      Xq, Wqb, bq, bk, bv, (void*)Qp);

  attn_kernel<<<dim3(SEQ / QT, 16, BATCH), 512, 0, stream>>>(Qp, Kp, Vtp, AO);

  gemm_bt<true><<<dim3(MROWS / 128, D_MODEL / 256, 1), 512, 0, stream>>>(
      AO, Wqb + 3 * WW, bo, bo, bo, d_out);
}